// Round 1
// 114.569 us; speedup vs baseline: 1.0348x; 1.0348x over previous
//
#include <hip/hip_runtime.h>

#define BATCH 500000
#define NF 20
#define NC 8
#define BLOCK 256
#define ROWF (2 * NF)          // 40 floats per input row
#define F4ROW (ROWF / 4)       // 10 float4 per row
#define STRIDE 41              // LDS row stride in floats; gcd(41,32)=1 -> conflict-free reads

__global__ __launch_bounds__(BLOCK) void nb_kernel(const float* __restrict__ x,
                                                   float* __restrict__ out) {
    // 256 rows * 41 floats * 4B = 41,984 B -> 3 blocks/CU (12 waves/CU), plenty to stream.
    __shared__ float tile[BLOCK * STRIDE];

    const int t    = threadIdx.x;
    const int row0 = blockIdx.x * BLOCK;
    const int nvalid = min(BLOCK, BATCH - row0);

    // ---- Coalesced staging: lane-contiguous float4 loads, padded LDS writes ----
    // Linear float4 index L = j*BLOCK + t: consecutive lanes -> consecutive 16B.
    // Each wave instruction covers 1KB contiguous (16 lines) instead of 64 lines.
    const float4* __restrict__ src = (const float4*)(x + (size_t)row0 * ROWF);

    if (nvalid == BLOCK) {
        #pragma unroll
        for (int j = 0; j < F4ROW; ++j) {
            int L = j * BLOCK + t;
            float4 v = src[L];
            int r = L / F4ROW;               // compile-time magic-mul (div by 10)
            int c = L - r * F4ROW;
            int a = r * STRIDE + c * 4;
            tile[a + 0] = v.x; tile[a + 1] = v.y; tile[a + 2] = v.z; tile[a + 3] = v.w;
        }
    } else {
        // tail block (32 rows): predicated staging
        int nv4 = nvalid * F4ROW;
        #pragma unroll
        for (int j = 0; j < F4ROW; ++j) {
            int L = j * BLOCK + t;
            if (L < nv4) {
                float4 v = src[L];
                int r = L / F4ROW;
                int c = L - r * F4ROW;
                int a = r * STRIDE + c * 4;
                tile[a + 0] = v.x; tile[a + 1] = v.y; tile[a + 2] = v.z; tile[a + 3] = v.w;
            }
        }
    }
    __syncthreads();

    // ---- Per-thread compute from private LDS row (stride 41 -> 2-way bank alias = free) ----
    const float* __restrict__ myrow = &tile[t * STRIDE];
    float feats[NF], mask[NF];
    #pragma unroll
    for (int f = 0; f < NF; ++f) feats[f] = myrow[f];
    #pragma unroll
    for (int f = 0; f < NF; ++f) mask[f] = myrow[NF + f];

    // indicator term per feature (contribution of a non-Gaussian feature)
    float term[NF];
    #pragma unroll
    for (int f = 0; f < NF; ++f) {
        float ind = (feats[f] >= 0.0f && feats[f] < 1.0f) ? 1.0f : 0.0f;
        term[f] = (mask[f] > 0.0f) ? ind : 1.0f;
    }

    // prefix/suffix products: class y's non-Gaussian product = pre[y]*suf[y+3]
    float pre[NF + 1], suf[NF + 1];
    pre[0] = 1.0f;
    #pragma unroll
    for (int f = 0; f < NF; ++f) pre[f + 1] = pre[f] * term[f];
    suf[NF] = 1.0f;
    #pragma unroll
    for (int f = NF - 1; f >= 0; --f) suf[f] = suf[f + 1] * term[f];

    const float inv_std = 1.0f / 0.3f;
    const float k_pdf   = 0.3989422804014327f / 0.3f;   // INV_SQRT_2PI / STD

    float probs[NC];
    float total = 0.0f;
    #pragma unroll
    for (int y = 0; y < NC; ++y) {
        float p = pre[y] * suf[y + 3];
        #pragma unroll
        for (int j = 0; j < 3; ++j) {
            int   f = y + j;
            float m = (float)((y >> j) & 1);
            float z = (feats[f] - m) * inv_std;
            float pdf = __expf(-0.5f * z * z) * k_pdf;
            p *= (mask[f] > 0.0f) ? pdf : 1.0f;
        }
        p *= 0.125f;                 // 1/NC before normalizer floor (matches reference)
        probs[y] = p;
        total += p;
    }

    float inv = 1.0f / fmaxf(total, 1e-8f);

    if (t < nvalid) {
        float4 o0 = make_float4(probs[0] * inv, probs[1] * inv, probs[2] * inv, probs[3] * inv);
        float4 o1 = make_float4(probs[4] * inv, probs[5] * inv, probs[6] * inv, probs[7] * inv);
        float4* ov = (float4*)(out + (size_t)(row0 + t) * NC);
        ov[0] = o0;
        ov[1] = o1;
    }
}

extern "C" void kernel_launch(void* const* d_in, const int* in_sizes, int n_in,
                              void* d_out, int out_size, void* d_ws, size_t ws_size,
                              hipStream_t stream) {
    const float* x = (const float*)d_in[0];
    float* out = (float*)d_out;
    int blocks = (BATCH + BLOCK - 1) / BLOCK;
    nb_kernel<<<blocks, BLOCK, 0, stream>>>(x, out);
}

// Round 2
// 113.332 us; speedup vs baseline: 1.0461x; 1.0109x over previous
//
#include <hip/hip_runtime.h>

#define BATCH 500000
#define NF 20
#define NC 8
#define BLOCK 64               // 1 wave per workgroup: staging is wave-local,
                               // __syncthreads is a free 1-wave barrier, and
                               // 10.5 KB LDS -> 15 blocks/CU (vs 3 at BLOCK=256)
#define ROWF (2 * NF)          // 40 floats per input row
#define F4ROW (ROWF / 4)       // 10 float4 per row
#define STRIDE 41              // LDS row stride; start bank = 9*t mod 32, bijective
                               // over 32 lanes -> 2-way across 64 lanes = free

__global__ __launch_bounds__(BLOCK) void nb_kernel(const float* __restrict__ x,
                                                   float* __restrict__ out) {
    __shared__ float tile[BLOCK * STRIDE];   // 64*41*4 = 10,496 B

    const int t    = threadIdx.x;
    const int row0 = blockIdx.x * BLOCK;
    const int nvalid = min(BLOCK, BATCH - row0);

    // ---- Wave-local coalesced staging ----
    // The wave's 64 rows = 2560 floats = 640 float4. Linear float4 index
    // L = j*64 + t: consecutive lanes -> consecutive 16B, so each of the 10
    // load instructions covers 1 KB contiguous (16 lines, minimal requests).
    const float4* __restrict__ src = (const float4*)(x + (size_t)row0 * ROWF);

    if (nvalid == BLOCK) {
        #pragma unroll
        for (int j = 0; j < F4ROW; ++j) {
            int L = j * BLOCK + t;
            float4 v = src[L];
            int r = L / F4ROW;               // compile-time magic-mul (div by 10)
            int c = L - r * F4ROW;
            int a = r * STRIDE + c * 4;
            tile[a + 0] = v.x; tile[a + 1] = v.y; tile[a + 2] = v.z; tile[a + 3] = v.w;
        }
    } else {
        // tail block (32 rows): predicated staging
        int nv4 = nvalid * F4ROW;
        #pragma unroll
        for (int j = 0; j < F4ROW; ++j) {
            int L = j * BLOCK + t;
            if (L < nv4) {
                float4 v = src[L];
                int r = L / F4ROW;
                int c = L - r * F4ROW;
                int a = r * STRIDE + c * 4;
                tile[a + 0] = v.x; tile[a + 1] = v.y; tile[a + 2] = v.z; tile[a + 3] = v.w;
            }
        }
    }
    __syncthreads();   // 1-wave workgroup: compiles to the lgkmcnt fence + immediate barrier

    // ---- Per-thread compute from private LDS row ----
    const float* __restrict__ myrow = &tile[t * STRIDE];
    float feats[NF], mask[NF];
    #pragma unroll
    for (int f = 0; f < NF; ++f) feats[f] = myrow[f];
    #pragma unroll
    for (int f = 0; f < NF; ++f) mask[f] = myrow[NF + f];

    // indicator term per feature (contribution of a non-Gaussian feature)
    float term[NF];
    #pragma unroll
    for (int f = 0; f < NF; ++f) {
        float ind = (feats[f] >= 0.0f && feats[f] < 1.0f) ? 1.0f : 0.0f;
        term[f] = (mask[f] > 0.0f) ? ind : 1.0f;
    }

    // prefix/suffix products: class y's non-Gaussian product = pre[y]*suf[y+3]
    float pre[NF + 1], suf[NF + 1];
    pre[0] = 1.0f;
    #pragma unroll
    for (int f = 0; f < NF; ++f) pre[f + 1] = pre[f] * term[f];
    suf[NF] = 1.0f;
    #pragma unroll
    for (int f = NF - 1; f >= 0; --f) suf[f] = suf[f + 1] * term[f];

    const float inv_std = 1.0f / 0.3f;
    const float k_pdf   = 0.3989422804014327f / 0.3f;   // INV_SQRT_2PI / STD

    float probs[NC];
    float total = 0.0f;
    #pragma unroll
    for (int y = 0; y < NC; ++y) {
        float p = pre[y] * suf[y + 3];
        #pragma unroll
        for (int j = 0; j < 3; ++j) {
            int   f = y + j;
            float m = (float)((y >> j) & 1);
            float z = (feats[f] - m) * inv_std;
            float pdf = __expf(-0.5f * z * z) * k_pdf;
            p *= (mask[f] > 0.0f) ? pdf : 1.0f;
        }
        p *= 0.125f;                 // 1/NC before normalizer floor (matches reference)
        probs[y] = p;
        total += p;
    }

    float inv = 1.0f / fmaxf(total, 1e-8f);

    if (t < nvalid) {
        float4 o0 = make_float4(probs[0] * inv, probs[1] * inv, probs[2] * inv, probs[3] * inv);
        float4 o1 = make_float4(probs[4] * inv, probs[5] * inv, probs[6] * inv, probs[7] * inv);
        float4* ov = (float4*)(out + (size_t)(row0 + t) * NC);
        ov[0] = o0;
        ov[1] = o1;
    }
}

extern "C" void kernel_launch(void* const* d_in, const int* in_sizes, int n_in,
                              void* d_out, int out_size, void* d_ws, size_t ws_size,
                              hipStream_t stream) {
    const float* x = (const float*)d_in[0];
    float* out = (float*)d_out;
    int blocks = (BATCH + BLOCK - 1) / BLOCK;
    nb_kernel<<<blocks, BLOCK, 0, stream>>>(x, out);
}